// Round 3
// baseline (83.896 us; speedup 1.0000x reference)
//
#include <hip/hip_runtime.h>

#define BATCH  262144
#define HIST   100
#define HIDDEN 128
#define NROWS2 131072   // threads in grid; each handles rows t and t+NROWS2

struct Acc { float sum, win0, win1, maxd; };

__device__ __forceinline__ void consume1(float4 v, Acc& a, bool early, bool recent) {
    // v = (success[2k], diff[2k], success[2k+1], diff[2k+1])
    float s2 = v.x + v.z;
    a.sum += s2;
    if (early)  a.win0 += s2;   // compile-time predicate
    if (recent) a.win1 += s2;   // compile-time predicate
    a.maxd = fmaxf(a.maxd, v.x > 0.5f ? v.y : 0.0f);
    a.maxd = fmaxf(a.maxd, v.z > 0.5f ? v.w : 0.0f);
}

__device__ __forceinline__ float finish_row(const float acc[32],
                                            const float* __restrict__ b2,
                                            const float* __restrict__ W3,
                                            const float* __restrict__ b3) {
    float o = b3[0];
    #pragma unroll
    for (int k = 0; k < 32; ++k)
        o = fmaf(fmaxf(acc[k] + b2[k], 0.0f), W3[k], o);  // +b2, relu, dot W3
    return 1.0f / (1.0f + __expf(-o));
}

// ~26 j's of layers 1+2 for the CURRENT row, with loads of 10 float4
// (20 timesteps) of the NEXT row issued up front so HBM latency hides
// under the ~1800 VALU cycles of this chunk. Chunk C covers float4
// indices [10C,10C+10): C==0 is exactly the early window, C==4 exactly
// the recent window -> all window predicates compile-time.
template<int C>
__device__ __forceinline__ void mlp_chunk(
    float f0, float f1, float f2, float acc[32],
    const float4* __restrict__ hB, Acc& aB,
    const float* __restrict__ W1, const float* __restrict__ b1,
    const float* __restrict__ W2)
{
    constexpr int J0 = (HIDDEN *  C)      / 5;   // 0,25,51,76,102
    constexpr int J1 = (HIDDEN * (C + 1)) / 5;   // 25,51,76,102,128

    float4 buf[10];
    #pragma unroll
    for (int i = 0; i < 10; ++i) buf[i] = hB[10 * C + i];

    #pragma unroll 2
    for (int j = J0; j < J1; ++j) {              // j wave-uniform -> s_loads
        float h = b1[j];
        h = fmaf(f0, W1[j], h);
        h = fmaf(f1, W1[HIDDEN + j], h);
        h = fmaf(f2, W1[2 * HIDDEN + j], h);
        h = fmaxf(h, 0.0f);
        const float4* __restrict__ w2v = (const float4*)(W2 + j * 32);
        #pragma unroll
        for (int q = 0; q < 8; ++q) {
            float4 w = w2v[q];
            acc[4*q+0] = fmaf(h, w.x, acc[4*q+0]);
            acc[4*q+1] = fmaf(h, w.y, acc[4*q+1]);
            acc[4*q+2] = fmaf(h, w.z, acc[4*q+2]);
            acc[4*q+3] = fmaf(h, w.w, acc[4*q+3]);
        }
    }

    #pragma unroll
    for (int i = 0; i < 10; ++i)
        consume1(buf[i], aB, C == 0, C == 4);
}

// Grid supplies exactly 2 waves/EU; tell the scheduler so it optimizes
// for ILP (deep load pipelining) instead of phantom occupancy.
__global__ __launch_bounds__(256)
__attribute__((amdgpu_waves_per_eu(2, 4)))
void competence_kernel(
    const float* __restrict__ hist,
    const float* __restrict__ W1, const float* __restrict__ b1,
    const float* __restrict__ W2, const float* __restrict__ b2,
    const float* __restrict__ W3, const float* __restrict__ b3,
    float* __restrict__ out)
{
    const int t = blockIdx.x * blockDim.x + threadIdx.x;

    const float4* __restrict__ hA =
        (const float4*)(hist + (size_t)t * (HIST * 2));
    const float4* __restrict__ hB =
        (const float4*)(hist + (size_t)(t + NROWS2) * (HIST * 2));

    // ---- phase 1: stream row A (50 independent loads, full unroll) ----
    Acc aA = {0.f, 0.f, 0.f, 0.f};
    #pragma unroll
    for (int k = 0; k < 50; ++k)
        consume1(hA[k], aA, k < 10, k >= 40);
    float f0 = aA.sum * 0.01f;
    float f1 = (aA.win1 - aA.win0) * 0.05f;
    float f2 = aA.maxd;

    // ---- phase 2: MLP for row A, interleaved with streaming row B ----
    float acc[32];
    #pragma unroll
    for (int k = 0; k < 32; ++k) acc[k] = 0.0f;   // b2 added in finish_row
    Acc aB = {0.f, 0.f, 0.f, 0.f};

    mlp_chunk<0>(f0, f1, f2, acc, hB, aB, W1, b1, W2);
    mlp_chunk<1>(f0, f1, f2, acc, hB, aB, W1, b1, W2);
    mlp_chunk<2>(f0, f1, f2, acc, hB, aB, W1, b1, W2);
    mlp_chunk<3>(f0, f1, f2, acc, hB, aB, W1, b1, W2);
    mlp_chunk<4>(f0, f1, f2, acc, hB, aB, W1, b1, W2);

    out[t] = finish_row(acc, b2, W3, b3);

    // ---- phase 3: MLP for row B ----
    float g0 = aB.sum * 0.01f;
    float g1 = (aB.win1 - aB.win0) * 0.05f;
    float g2 = aB.maxd;

    float acc2[32];
    #pragma unroll
    for (int k = 0; k < 32; ++k) acc2[k] = 0.0f;

    #pragma unroll 2
    for (int j = 0; j < HIDDEN; ++j) {
        float h = b1[j];
        h = fmaf(g0, W1[j], h);
        h = fmaf(g1, W1[HIDDEN + j], h);
        h = fmaf(g2, W1[2 * HIDDEN + j], h);
        h = fmaxf(h, 0.0f);
        const float4* __restrict__ w2v = (const float4*)(W2 + j * 32);
        #pragma unroll
        for (int q = 0; q < 8; ++q) {
            float4 w = w2v[q];
            acc2[4*q+0] = fmaf(h, w.x, acc2[4*q+0]);
            acc2[4*q+1] = fmaf(h, w.y, acc2[4*q+1]);
            acc2[4*q+2] = fmaf(h, w.z, acc2[4*q+2]);
            acc2[4*q+3] = fmaf(h, w.w, acc2[4*q+3]);
        }
    }

    out[t + NROWS2] = finish_row(acc2, b2, W3, b3);
}

extern "C" void kernel_launch(void* const* d_in, const int* in_sizes, int n_in,
                              void* d_out, int out_size, void* d_ws, size_t ws_size,
                              hipStream_t stream) {
    const float* hist = (const float*)d_in[0];
    const float* W1   = (const float*)d_in[1];
    const float* b1   = (const float*)d_in[2];
    const float* W2   = (const float*)d_in[3];
    const float* b2   = (const float*)d_in[4];
    const float* W3   = (const float*)d_in[5];
    const float* b3   = (const float*)d_in[6];
    float* out = (float*)d_out;

    const int threads = 256;
    const int blocks  = NROWS2 / threads;   // 512 blocks = 2048 waves = 8/CU
    competence_kernel<<<blocks, threads, 0, stream>>>(
        hist, W1, b1, W2, b2, W3, b3, out);
}

// Round 4
// 64.466 us; speedup vs baseline: 1.3014x; 1.3014x over previous
//
#include <hip/hip_runtime.h>

#define BATCH  262144
#define HIST   100
#define HIDDEN 128
#define ROWS_PER_BLOCK 256
#define F4_PER_CHUNK   10            // 10 float4 = 20 timesteps per row per chunk
#define CHUNK_SLOTS    (ROWS_PER_BLOCK * F4_PER_CHUNK)   // 2560 float4 = 40 KB

// One block = 256 rows. 5 time-chunks; chunk c covers timesteps [20c, 20c+20),
// so chunk 0 == early window, chunk 4 == recent window (compile-time predicates).
// Stage: global -> LDS via global_load_lds width16, fully coalesced (each wave
// instruction reads 1024 contiguous LDS-dest bytes; global sources are per-lane).
// Consume: thread t reads its own row t back with ds_read_b128 (160B stride:
// ~2x LDS phase cost, acceptable). MLP: per-thread, wave-uniform s_load weights.
__global__ __launch_bounds__(256) void competence_kernel(
    const float* __restrict__ hist,
    const float* __restrict__ W1, const float* __restrict__ b1,
    const float* __restrict__ W2, const float* __restrict__ b2,
    const float* __restrict__ W3, const float* __restrict__ b3,
    float* __restrict__ out)
{
    __shared__ float4 tile[CHUNK_SLOTS];   // 40 KB -> 4 blocks/CU

    const int t    = threadIdx.x;
    const int lane = t & 63;
    const int w    = t >> 6;               // wave id in block (uniform per wave)
    const size_t blockBase = (size_t)blockIdx.x * ROWS_PER_BLOCK * (HIST * 2);

    float sum = 0.0f, early = 0.0f, recent = 0.0f, maxd = 0.0f;

    #pragma unroll
    for (int c = 0; c < 5; ++c) {
        // ---- stage chunk c: 10 global_load_lds per thread-slot, coalesced ----
        #pragma unroll
        for (int i = 0; i < 10; ++i) {
            const int f   = i * 256 + w * 64 + lane;       // linear LDS slot
            const int row = (f * 6554) >> 16;              // f / 10 (f < 2560)
            const int idx = f - row * 10;                  // f % 10
            const float* src = hist + blockBase
                             + (size_t)row * (HIST * 2) + c * 40 + idx * 4;
            __builtin_amdgcn_global_load_lds(
                (const __attribute__((address_space(1))) void*)src,
                (__attribute__((address_space(3))) void*)&tile[i * 256 + w * 64],
                16, 0, 0);
        }
        __syncthreads();   // compiler drains vmcnt before the barrier

        // ---- consume: thread t owns row t ----
        #pragma unroll
        for (int idx = 0; idx < 10; ++idx) {
            float4 v = tile[t * F4_PER_CHUNK + idx];
            float s2 = v.x + v.z;
            sum += s2;
            if (c == 0) early  += s2;      // compile-time (c is unrolled)
            if (c == 4) recent += s2;
            maxd = fmaxf(maxd, v.x > 0.5f ? v.y : 0.0f);
            maxd = fmaxf(maxd, v.z > 0.5f ? v.w : 0.0f);
        }
        __syncthreads();   // protect tile before next chunk's stage
    }

    const float f0 = sum * 0.01f;                 // success_rate
    const float f1 = (recent - early) * 0.05f;    // improvement_trend
    const float f2 = maxd;                        // max_difficulty_handled

    // ---- fused MLP (round-1 proven code) ----
    float acc[32];
    #pragma unroll
    for (int k = 0; k < 32; ++k) acc[k] = b2[k];

    #pragma unroll 2
    for (int j = 0; j < HIDDEN; ++j) {
        float h = b1[j];
        h = fmaf(f0, W1[j], h);
        h = fmaf(f1, W1[HIDDEN + j], h);
        h = fmaf(f2, W1[2 * HIDDEN + j], h);
        h = fmaxf(h, 0.0f);                       // relu
        const float4* __restrict__ w2v = (const float4*)(W2 + j * 32);
        #pragma unroll
        for (int q = 0; q < 8; ++q) {
            float4 wv = w2v[q];
            acc[4*q+0] = fmaf(h, wv.x, acc[4*q+0]);
            acc[4*q+1] = fmaf(h, wv.y, acc[4*q+1]);
            acc[4*q+2] = fmaf(h, wv.z, acc[4*q+2]);
            acc[4*q+3] = fmaf(h, wv.w, acc[4*q+3]);
        }
    }

    float o = b3[0];
    #pragma unroll
    for (int k = 0; k < 32; ++k)
        o = fmaf(fmaxf(acc[k], 0.0f), W3[k], o);  // relu + final dot

    out[blockIdx.x * ROWS_PER_BLOCK + t] = 1.0f / (1.0f + __expf(-o));
}

extern "C" void kernel_launch(void* const* d_in, const int* in_sizes, int n_in,
                              void* d_out, int out_size, void* d_ws, size_t ws_size,
                              hipStream_t stream) {
    const float* hist = (const float*)d_in[0];
    const float* W1   = (const float*)d_in[1];
    const float* b1   = (const float*)d_in[2];
    const float* W2   = (const float*)d_in[3];
    const float* b2   = (const float*)d_in[4];
    const float* W3   = (const float*)d_in[5];
    const float* b3   = (const float*)d_in[6];
    float* out = (float*)d_out;

    const int threads = 256;
    const int blocks  = BATCH / ROWS_PER_BLOCK;   // 1024
    competence_kernel<<<blocks, threads, 0, stream>>>(
        hist, W1, b1, W2, b2, W3, b3, out);
}

// Round 5
// 44.731 us; speedup vs baseline: 1.8755x; 1.4412x over previous
//
#include <hip/hip_runtime.h>
#include <stdint.h>

#define BATCH  262144
#define HIST   100
#define HIDDEN 128

typedef __attribute__((ext_vector_type(8))) short short8_t;  // 8 bf16
typedef __attribute__((ext_vector_type(4))) float f32x4;

__device__ __forceinline__ uint32_t cvt_pk_bf16(float lo, float hi) {
    uint32_t d;
    asm("v_cvt_pk_bf16_f32 %0, %1, %2" : "=v"(d) : "v"(lo), "v"(hi));
    return d;   // d[15:0]=bf16(lo), d[31:16]=bf16(hi)
}

union FragU { uint32_t u[4]; short8_t s8; uint4 u4; };

// Block = 256 threads = 256 rows. Phases:
//  1) stream own row (round-1 proven pattern), features f0,f1,f2
//  2) layer 1 on VALU (128 x 4 ops), pack bf16, write swizzled per-wave
//     LDS tile (64 rows x 128B, XOR j8^(r&7) -> conflict-free b128 r/w)
//  3) layer 2 on MFMA 16x16x32 bf16: 4 row-groups x 2 N-tiles x 4 K-steps
//     (A read from own wave's tile -> NO __syncthreads anywhere)
//  4) epilogue: relu+b2, dot W3 via shfl_xor reduce, sigmoid, float4 store
__global__ __launch_bounds__(256) void competence_kernel(
    const float* __restrict__ hist,
    const float* __restrict__ W1, const float* __restrict__ b1,
    const float* __restrict__ W2, const float* __restrict__ b2,
    const float* __restrict__ W3, const float* __restrict__ b3,
    float* __restrict__ out)
{
    __shared__ uint32_t h1t[8192];   // 32 KB = 4 wave-regions x 64 rows x 32 dw

    const int t    = threadIdx.x;
    const int lane = t & 63;
    const int w    = t >> 6;
    const int row  = blockIdx.x * 256 + t;

    // ---------------- phase 1: stream (round-1 pattern, static windows) ----
    const float4* __restrict__ h4 =
        (const float4*)(hist + (size_t)row * (HIST * 2));

    float sum = 0.f, early = 0.f, recent = 0.f, maxd = 0.f;
    #pragma unroll
    for (int k = 0; k < 10; ++k) {              // timesteps 0..19 (early)
        float4 v = h4[k];
        float s2 = v.x + v.z;
        sum += s2; early += s2;
        maxd = fmaxf(maxd, v.x > 0.5f ? v.y : 0.0f);
        maxd = fmaxf(maxd, v.z > 0.5f ? v.w : 0.0f);
    }
    #pragma unroll 10
    for (int k = 10; k < 40; ++k) {             // middle
        float4 v = h4[k];
        float s2 = v.x + v.z;
        sum += s2;
        maxd = fmaxf(maxd, v.x > 0.5f ? v.y : 0.0f);
        maxd = fmaxf(maxd, v.z > 0.5f ? v.w : 0.0f);
    }
    #pragma unroll
    for (int k = 40; k < 50; ++k) {             // timesteps 80..99 (recent)
        float4 v = h4[k];
        float s2 = v.x + v.z;
        sum += s2; recent += s2;
        maxd = fmaxf(maxd, v.x > 0.5f ? v.y : 0.0f);
        maxd = fmaxf(maxd, v.z > 0.5f ? v.w : 0.0f);
    }
    const float f0 = sum * 0.01f;
    const float f1 = (recent - early) * 0.05f;
    const float f2 = maxd;

    // ---------------- B fragments (W2 -> bf16) + per-lane b2/W3 slices -----
    const int cl = lane & 15;       // col within 16-tile / row within A-group
    const int ko = lane >> 4;       // k-octet selector
    const float b2v0 = b2[cl],      b2v1 = b2[16 + cl];
    const float w3v0 = W3[cl],      w3v1 = W3[16 + cl];
    const float b3v  = b3[0];

    short8_t bfr[8];                            // [kstep s][ntile n] = s*2+n
    #pragma unroll
    for (int s = 0; s < 4; ++s) {
        #pragma unroll
        for (int n = 0; n < 2; ++n) {
            float wv[8];
            #pragma unroll
            for (int i = 0; i < 8; ++i)         // k = 32s + 8*ko + i
                wv[i] = W2[(32 * s + 8 * ko + i) * 32 + n * 16 + cl];
            FragU fu;
            #pragma unroll
            for (int q = 0; q < 4; ++q)
                fu.u[q] = cvt_pk_bf16(wv[2 * q], wv[2 * q + 1]);
            bfr[s * 2 + n] = fu.s8;
        }
    }

    f32x4 acc[4][2];
    #pragma unroll
    for (int g = 0; g < 4; ++g)
        #pragma unroll
        for (int n = 0; n < 2; ++n)
            acc[g][n] = (f32x4){0.f, 0.f, 0.f, 0.f};

    const int r     = lane;        // row within this wave's tile
    const int wbase = w * 2048;    // dword base of wave region

    #pragma unroll
    for (int hh = 0; hh < 2; ++hh) {           // K halves: j in [64hh, 64hh+64)
        // ---- layer 1 for this half: compute, pack, swizzled LDS write ----
        #pragma unroll
        for (int j8 = 0; j8 < 8; ++j8) {
            FragU pk;
            #pragma unroll
            for (int q = 0; q < 4; ++q) {
                const int j = hh * 64 + j8 * 8 + q * 2;
                float h0 = fmaf(f2, W1[256 + j],
                            fmaf(f1, W1[128 + j], fmaf(f0, W1[j], b1[j])));
                float h1 = fmaf(f2, W1[256 + j + 1],
                            fmaf(f1, W1[128 + j + 1],
                                 fmaf(f0, W1[j + 1], b1[j + 1])));
                pk.u[q] = cvt_pk_bf16(fmaxf(h0, 0.f), fmaxf(h1, 0.f));
            }
            *(uint4*)&h1t[wbase + r * 32 + ((j8 ^ (r & 7)) << 2)] = pk.u4;
        }
        // ---- MFMA for this half (reads only this wave's own rows) ----
        #pragma unroll
        for (int g = 0; g < 4; ++g) {
            const int arow = g * 16 + cl;
            #pragma unroll
            for (int sp = 0; sp < 2; ++sp) {
                const int j8r = sp * 4 + ko;   // k-octet within half
                short8_t a = *(const short8_t*)
                    &h1t[wbase + arow * 32 + ((j8r ^ (arow & 7)) << 2)];
                const int s = hh * 2 + sp;     // global K-step 0..3
                acc[g][0] = __builtin_amdgcn_mfma_f32_16x16x32_bf16(
                    a, bfr[s * 2 + 0], acc[g][0], 0, 0, 0);
                acc[g][1] = __builtin_amdgcn_mfma_f32_16x16x32_bf16(
                    a, bfr[s * 2 + 1], acc[g][1], 0, 0, 0);
            }
        }
    }

    // ---------------- epilogue: relu+b2, dot W3, reduce, sigmoid, store ----
    #pragma unroll
    for (int g = 0; g < 4; ++g) {
        float o[4];
        #pragma unroll
        for (int p = 0; p < 4; ++p) {
            float v0 = fmaxf(acc[g][0][p] + b2v0, 0.f) * w3v0;
            float v1 = fmaxf(acc[g][1][p] + b2v1, 0.f) * w3v1;
            o[p] = v0 + v1;
        }
        #pragma unroll
        for (int m = 1; m < 16; m <<= 1)
            #pragma unroll
            for (int p = 0; p < 4; ++p)
                o[p] += __shfl_xor(o[p], m);
        if (cl == 0) {
            float4 res;
            res.x = 1.f / (1.f + __expf(-(o[0] + b3v)));
            res.y = 1.f / (1.f + __expf(-(o[1] + b3v)));
            res.z = 1.f / (1.f + __expf(-(o[2] + b3v)));
            res.w = 1.f / (1.f + __expf(-(o[3] + b3v)));
            *(float4*)&out[blockIdx.x * 256 + w * 64 + g * 16 + ko * 4] = res;
        }
    }
}

extern "C" void kernel_launch(void* const* d_in, const int* in_sizes, int n_in,
                              void* d_out, int out_size, void* d_ws, size_t ws_size,
                              hipStream_t stream) {
    const float* hist = (const float*)d_in[0];
    const float* W1   = (const float*)d_in[1];
    const float* b1   = (const float*)d_in[2];
    const float* W2   = (const float*)d_in[3];
    const float* b2   = (const float*)d_in[4];
    const float* W3   = (const float*)d_in[5];
    const float* b3   = (const float*)d_in[6];
    float* out = (float*)d_out;

    const int threads = 256;
    const int blocks  = BATCH / 256;   // 1024 blocks -> 4 blocks/CU, 16 waves/CU
    competence_kernel<<<blocks, threads, 0, stream>>>(
        hist, W1, b1, W2, b2, W3, b3, out);
}

// Round 6
// 42.427 us; speedup vs baseline: 1.9774x; 1.0543x over previous
//
#include <hip/hip_runtime.h>
#include <stdint.h>

#define BATCH  262144
#define HIST   100
#define HIDDEN 128

typedef __attribute__((ext_vector_type(8))) short short8_t;  // 8 bf16
typedef __attribute__((ext_vector_type(4))) float f32x4;

__device__ __forceinline__ uint32_t cvt_pk_bf16(float lo, float hi) {
    uint32_t d;
    asm("v_cvt_pk_bf16_f32 %0, %1, %2" : "=v"(d) : "v"(lo), "v"(hi));
    return d;   // d[15:0]=bf16(lo), d[31:16]=bf16(hi)
}

union FragU { uint32_t u[4]; short8_t s8; uint4 u4; };

// Block = 256 threads = 256 rows, one wave = 64 rows, NO inter-wave deps
// except one redistribute barrier.
//  1) stream: 4 lanes per row (lane=4r+q reads float4s {4i+q}) -> every wave
//     load = 16 rows x 64 contiguous bytes = 16 fully-consumed cache lines
//     (copy-class coalescing, no L1-re-hit reliance). 4-lane shfl_xor reduce,
//     LDS redistribute so lane=row again.
//  2) layer 1 on VALU, pack bf16, swizzled per-wave LDS tile
//  3) layer 2 on MFMA 16x16x32 bf16 (wave-local, no barriers)
//  4) epilogue: relu+b2, dot W3 via shfl reduce, sigmoid, float4 store
__global__ __launch_bounds__(256) void competence_kernel(
    const float* __restrict__ hist,
    const float* __restrict__ W1, const float* __restrict__ b1,
    const float* __restrict__ W2, const float* __restrict__ b2,
    const float* __restrict__ W3, const float* __restrict__ b3,
    float* __restrict__ out)
{
    __shared__ uint32_t h1t[8192];   // 32 KB: 4 wave-regions x 64 rows x 32 dw
    __shared__ float4  feat[256];    // 4 KB: features, lane=row redistribute

    const int t    = threadIdx.x;
    const int lane = t & 63;
    const int w    = t >> 6;
    const int q    = lane & 3;       // float4-phase within row
    const int rr   = lane >> 2;      // row within 16-row group
    const size_t wrow0 = (size_t)blockIdx.x * 256 + w * 64;

    // ---------------- phase 1: copy-class streaming ----------------
    #pragma unroll
    for (int g = 0; g < 4; ++g) {
        const float4* __restrict__ h4 =
            (const float4*)(hist + (wrow0 + g * 16 + rr) * (HIST * 2));
        float sum = 0.f, early = 0.f, recent = 0.f, maxd = 0.f;
        #pragma unroll
        for (int i = 0; i < 12; ++i) {           // float4 idx = 4i+q in [0,48)
            float4 v = h4[4 * i + q];
            float s2 = v.x + v.z;
            sum += s2;
            if (i < 2)       early += s2;                    // idx 0..7
            else if (i == 2) early += (q < 2) ? s2 : 0.f;    // idx 8,9 only
            if (i >= 10)     recent += s2;                   // idx 40..47
            maxd = fmaxf(maxd, v.x > 0.5f ? v.y : 0.0f);
            maxd = fmaxf(maxd, v.z > 0.5f ? v.w : 0.0f);
        }
        if (q < 2) {                             // tail: float4 idx 48,49
            float4 v = h4[48 + q];
            float s2 = v.x + v.z;
            sum += s2; recent += s2;
            maxd = fmaxf(maxd, v.x > 0.5f ? v.y : 0.0f);
            maxd = fmaxf(maxd, v.z > 0.5f ? v.w : 0.0f);
        }
        // reduce across the 4 lanes of this row
        float rme = recent - early;
        #pragma unroll
        for (int m = 1; m < 4; m <<= 1) {
            sum  += __shfl_xor(sum, m);
            rme  += __shfl_xor(rme, m);
            maxd  = fmaxf(maxd, __shfl_xor(maxd, m));
        }
        if (q == 0)
            feat[w * 64 + g * 16 + rr] =
                make_float4(sum * 0.01f, rme * 0.05f, maxd, 0.f);
    }
    __syncthreads();

    const float4 F = feat[w * 64 + lane];
    const float f0 = F.x, f1 = F.y, f2 = F.z;

    // ---------------- B fragments (W2 -> bf16) + per-lane b2/W3 slices -----
    const int cl = lane & 15;
    const int ko = lane >> 4;
    const float b2v0 = b2[cl],  b2v1 = b2[16 + cl];
    const float w3v0 = W3[cl],  w3v1 = W3[16 + cl];
    const float b3v  = b3[0];

    short8_t bfr[8];                             // [kstep s][ntile n] = s*2+n
    #pragma unroll
    for (int s = 0; s < 4; ++s) {
        #pragma unroll
        for (int n = 0; n < 2; ++n) {
            float wv[8];
            #pragma unroll
            for (int i = 0; i < 8; ++i)          // k = 32s + 8*ko + i
                wv[i] = W2[(32 * s + 8 * ko + i) * 32 + n * 16 + cl];
            FragU fu;
            #pragma unroll
            for (int p = 0; p < 4; ++p)
                fu.u[p] = cvt_pk_bf16(wv[2 * p], wv[2 * p + 1]);
            bfr[s * 2 + n] = fu.s8;
        }
    }

    f32x4 acc[4][2];
    #pragma unroll
    for (int g = 0; g < 4; ++g)
        #pragma unroll
        for (int n = 0; n < 2; ++n)
            acc[g][n] = (f32x4){0.f, 0.f, 0.f, 0.f};

    const int r     = lane;
    const int wbase = w * 2048;

    #pragma unroll
    for (int hh = 0; hh < 2; ++hh) {             // K halves: j in [64hh,64hh+64)
        // ---- layer 1 for this half: compute, pack, swizzled LDS write ----
        #pragma unroll
        for (int j8 = 0; j8 < 8; ++j8) {
            FragU pk;
            #pragma unroll
            for (int p = 0; p < 4; ++p) {
                const int j = hh * 64 + j8 * 8 + p * 2;
                float h0 = fmaf(f2, W1[256 + j],
                            fmaf(f1, W1[128 + j], fmaf(f0, W1[j], b1[j])));
                float h1 = fmaf(f2, W1[256 + j + 1],
                            fmaf(f1, W1[128 + j + 1],
                                 fmaf(f0, W1[j + 1], b1[j + 1])));
                pk.u[p] = cvt_pk_bf16(fmaxf(h0, 0.f), fmaxf(h1, 0.f));
            }
            *(uint4*)&h1t[wbase + r * 32 + ((j8 ^ (r & 7)) << 2)] = pk.u4;
        }
        // ---- MFMA for this half (reads only this wave's own rows) ----
        #pragma unroll
        for (int g = 0; g < 4; ++g) {
            const int arow = g * 16 + cl;
            #pragma unroll
            for (int sp = 0; sp < 2; ++sp) {
                const int j8r = sp * 4 + ko;
                short8_t a = *(const short8_t*)
                    &h1t[wbase + arow * 32 + ((j8r ^ (arow & 7)) << 2)];
                const int s = hh * 2 + sp;
                acc[g][0] = __builtin_amdgcn_mfma_f32_16x16x32_bf16(
                    a, bfr[s * 2 + 0], acc[g][0], 0, 0, 0);
                acc[g][1] = __builtin_amdgcn_mfma_f32_16x16x32_bf16(
                    a, bfr[s * 2 + 1], acc[g][1], 0, 0, 0);
            }
        }
    }

    // ---------------- epilogue ----------------
    #pragma unroll
    for (int g = 0; g < 4; ++g) {
        float o[4];
        #pragma unroll
        for (int p = 0; p < 4; ++p) {
            float v0 = fmaxf(acc[g][0][p] + b2v0, 0.f) * w3v0;
            float v1 = fmaxf(acc[g][1][p] + b2v1, 0.f) * w3v1;
            o[p] = v0 + v1;
        }
        #pragma unroll
        for (int m = 1; m < 16; m <<= 1)
            #pragma unroll
            for (int p = 0; p < 4; ++p)
                o[p] += __shfl_xor(o[p], m);
        if (cl == 0) {
            float4 res;
            res.x = 1.f / (1.f + __expf(-(o[0] + b3v)));
            res.y = 1.f / (1.f + __expf(-(o[1] + b3v)));
            res.z = 1.f / (1.f + __expf(-(o[2] + b3v)));
            res.w = 1.f / (1.f + __expf(-(o[3] + b3v)));
            *(float4*)&out[blockIdx.x * 256 + w * 64 + g * 16 + ko * 4] = res;
        }
    }
}

extern "C" void kernel_launch(void* const* d_in, const int* in_sizes, int n_in,
                              void* d_out, int out_size, void* d_ws, size_t ws_size,
                              hipStream_t stream) {
    const float* hist = (const float*)d_in[0];
    const float* W1   = (const float*)d_in[1];
    const float* b1   = (const float*)d_in[2];
    const float* W2   = (const float*)d_in[3];
    const float* b2   = (const float*)d_in[4];
    const float* W3   = (const float*)d_in[5];
    const float* b3   = (const float*)d_in[6];
    float* out = (float*)d_out;

    const int threads = 256;
    const int blocks  = BATCH / 256;   // 1024 blocks -> 4 blocks/CU
    competence_kernel<<<blocks, threads, 0, stream>>>(
        hist, W1, b1, W2, b2, W3, b3, out);
}

// Round 7
// 41.632 us; speedup vs baseline: 2.0152x; 1.0191x over previous
//
#include <hip/hip_runtime.h>
#include <stdint.h>

#define BATCH  262144
#define HIST   100
#define HIDDEN 128

typedef __attribute__((ext_vector_type(8))) short short8_t;  // 8 bf16
typedef __attribute__((ext_vector_type(4))) float f32x4;

__device__ __forceinline__ uint32_t cvt_pk_bf16(float lo, float hi) {
    uint32_t d;
    asm("v_cvt_pk_bf16_f32 %0, %1, %2" : "=v"(d) : "v"(lo), "v"(hi));
    return d;   // d[15:0]=bf16(lo), d[31:16]=bf16(hi)
}

union FragU { uint32_t u[4]; short8_t s8; uint4 u4; };

// ONE WAVE per block (64 rows), 4096 blocks -> 16 independent wave-units
// per CU, free to drift (no __syncthreads anywhere) so streaming waves
// keep the memory pipe fed while others run the MLP.
//  1) stream: 4 lanes per row (copy-class full-line coalescing),
//     4-lane shfl_xor butterfly, in-wave shfl redistribute (no LDS)
//  2) layer 1 on VALU, pack bf16, swizzled 8KB LDS tile (wave-local)
//  3) layer 2 on MFMA 16x16x32 bf16
//  4) epilogue: relu+b2, dot W3 via shfl reduce, sigmoid, float4 store
__global__ __launch_bounds__(64) void competence_kernel(
    const float* __restrict__ hist,
    const float* __restrict__ W1, const float* __restrict__ b1,
    const float* __restrict__ W2, const float* __restrict__ b2,
    const float* __restrict__ W3, const float* __restrict__ b3,
    float* __restrict__ out)
{
    __shared__ uint32_t h1t[2048];   // 8 KB: 64 rows x 32 dw, XOR-swizzled

    const int lane = threadIdx.x;    // 0..63
    const int q    = lane & 3;       // float4-phase within row
    const int rr   = lane >> 2;      // row within 16-row group
    const size_t row0 = (size_t)blockIdx.x * 64;

    // ---------------- phase 1: copy-class streaming ----------------
    float fsum[4], frme[4], fmax[4];
    #pragma unroll
    for (int g = 0; g < 4; ++g) {
        const float4* __restrict__ h4 =
            (const float4*)(hist + (row0 + g * 16 + rr) * (HIST * 2));
        float sum = 0.f, early = 0.f, recent = 0.f, maxd = 0.f;
        #pragma unroll
        for (int i = 0; i < 12; ++i) {           // float4 idx = 4i+q in [0,48)
            float4 v = h4[4 * i + q];
            float s2 = v.x + v.z;
            sum += s2;
            if (i < 2)       early += s2;                    // idx 0..7
            else if (i == 2) early += (q < 2) ? s2 : 0.f;    // idx 8,9 only
            if (i >= 10)     recent += s2;                   // idx 40..47
            maxd = fmaxf(maxd, v.x > 0.5f ? v.y : 0.0f);
            maxd = fmaxf(maxd, v.z > 0.5f ? v.w : 0.0f);
        }
        if (q < 2) {                             // tail: float4 idx 48,49
            float4 v = h4[48 + q];
            float s2 = v.x + v.z;
            sum += s2; recent += s2;
            maxd = fmaxf(maxd, v.x > 0.5f ? v.y : 0.0f);
            maxd = fmaxf(maxd, v.z > 0.5f ? v.w : 0.0f);
        }
        float rme = recent - early;
        #pragma unroll
        for (int m = 1; m < 4; m <<= 1) {        // full butterfly: all 4 lanes
            sum += __shfl_xor(sum, m);
            rme += __shfl_xor(rme, m);
            maxd = fmaxf(maxd, __shfl_xor(maxd, m));
        }
        fsum[g] = sum; frme[g] = rme; fmax[g] = maxd;
    }

    // in-wave redistribute: thread `lane` = row g'*16+rr' needs group g'
    // triple from source lane 4*rr' (butterfly left it in all 4 lanes)
    const int src  = (lane & 15) << 2;
    const int gsel = lane >> 4;
    float s0 = __shfl(fsum[0], src), s1 = __shfl(fsum[1], src),
          s2 = __shfl(fsum[2], src), s3 = __shfl(fsum[3], src);
    float r0 = __shfl(frme[0], src), r1 = __shfl(frme[1], src),
          r2 = __shfl(frme[2], src), r3 = __shfl(frme[3], src);
    float m0 = __shfl(fmax[0], src), m1 = __shfl(fmax[1], src),
          m2 = __shfl(fmax[2], src), m3 = __shfl(fmax[3], src);
    const float f0 = ((gsel & 2) ? ((gsel & 1) ? s3 : s2)
                                 : ((gsel & 1) ? s1 : s0)) * 0.01f;
    const float f1 = ((gsel & 2) ? ((gsel & 1) ? r3 : r2)
                                 : ((gsel & 1) ? r1 : r0)) * 0.05f;
    const float f2 =  (gsel & 2) ? ((gsel & 1) ? m3 : m2)
                                 : ((gsel & 1) ? m1 : m0);

    // ---------------- B fragments (W2 -> bf16) + per-lane b2/W3 slices -----
    const int cl = lane & 15;
    const int ko = lane >> 4;
    const float b2v0 = b2[cl],  b2v1 = b2[16 + cl];
    const float w3v0 = W3[cl],  w3v1 = W3[16 + cl];
    const float b3v  = b3[0];

    short8_t bfr[8];                             // [kstep s][ntile n] = s*2+n
    #pragma unroll
    for (int s = 0; s < 4; ++s) {
        #pragma unroll
        for (int n = 0; n < 2; ++n) {
            float wv[8];
            #pragma unroll
            for (int i = 0; i < 8; ++i)          // k = 32s + 8*ko + i
                wv[i] = W2[(32 * s + 8 * ko + i) * 32 + n * 16 + cl];
            FragU fu;
            #pragma unroll
            for (int p = 0; p < 4; ++p)
                fu.u[p] = cvt_pk_bf16(wv[2 * p], wv[2 * p + 1]);
            bfr[s * 2 + n] = fu.s8;
        }
    }

    f32x4 acc[4][2];
    #pragma unroll
    for (int g = 0; g < 4; ++g)
        #pragma unroll
        for (int n = 0; n < 2; ++n)
            acc[g][n] = (f32x4){0.f, 0.f, 0.f, 0.f};

    const int r = lane;

    #pragma unroll
    for (int hh = 0; hh < 2; ++hh) {             // K halves: j in [64hh,64hh+64)
        // ---- layer 1 for this half: compute, pack, swizzled LDS write ----
        #pragma unroll
        for (int j8 = 0; j8 < 8; ++j8) {
            FragU pk;
            #pragma unroll
            for (int p = 0; p < 4; ++p) {
                const int j = hh * 64 + j8 * 8 + p * 2;
                float h0 = fmaf(f2, W1[256 + j],
                            fmaf(f1, W1[128 + j], fmaf(f0, W1[j], b1[j])));
                float h1 = fmaf(f2, W1[256 + j + 1],
                            fmaf(f1, W1[128 + j + 1],
                                 fmaf(f0, W1[j + 1], b1[j + 1])));
                pk.u[p] = cvt_pk_bf16(fmaxf(h0, 0.f), fmaxf(h1, 0.f));
            }
            *(uint4*)&h1t[r * 32 + ((j8 ^ (r & 7)) << 2)] = pk.u4;
        }
        // ---- MFMA for this half (wave-local LDS, no barrier needed) ----
        #pragma unroll
        for (int g = 0; g < 4; ++g) {
            const int arow = g * 16 + cl;
            #pragma unroll
            for (int sp = 0; sp < 2; ++sp) {
                const int j8r = sp * 4 + ko;
                short8_t a = *(const short8_t*)
                    &h1t[arow * 32 + ((j8r ^ (arow & 7)) << 2)];
                const int s = hh * 2 + sp;
                acc[g][0] = __builtin_amdgcn_mfma_f32_16x16x32_bf16(
                    a, bfr[s * 2 + 0], acc[g][0], 0, 0, 0);
                acc[g][1] = __builtin_amdgcn_mfma_f32_16x16x32_bf16(
                    a, bfr[s * 2 + 1], acc[g][1], 0, 0, 0);
            }
        }
    }

    // ---------------- epilogue ----------------
    #pragma unroll
    for (int g = 0; g < 4; ++g) {
        float o[4];
        #pragma unroll
        for (int p = 0; p < 4; ++p) {
            float v0 = fmaxf(acc[g][0][p] + b2v0, 0.f) * w3v0;
            float v1 = fmaxf(acc[g][1][p] + b2v1, 0.f) * w3v1;
            o[p] = v0 + v1;
        }
        #pragma unroll
        for (int m = 1; m < 16; m <<= 1)
            #pragma unroll
            for (int p = 0; p < 4; ++p)
                o[p] += __shfl_xor(o[p], m);
        if (cl == 0) {
            float4 res;
            res.x = 1.f / (1.f + __expf(-(o[0] + b3v)));
            res.y = 1.f / (1.f + __expf(-(o[1] + b3v)));
            res.z = 1.f / (1.f + __expf(-(o[2] + b3v)));
            res.w = 1.f / (1.f + __expf(-(o[3] + b3v)));
            *(float4*)&out[blockIdx.x * 64 + g * 16 + ko * 4] = res;
        }
    }
}

extern "C" void kernel_launch(void* const* d_in, const int* in_sizes, int n_in,
                              void* d_out, int out_size, void* d_ws, size_t ws_size,
                              hipStream_t stream) {
    const float* hist = (const float*)d_in[0];
    const float* W1   = (const float*)d_in[1];
    const float* b1   = (const float*)d_in[2];
    const float* W2   = (const float*)d_in[3];
    const float* b2   = (const float*)d_in[4];
    const float* W3   = (const float*)d_in[5];
    const float* b3   = (const float*)d_in[6];
    float* out = (float*)d_out;

    const int threads = 64;            // one wave per block
    const int blocks  = BATCH / 64;    // 4096 blocks -> 16 wave-units/CU
    competence_kernel<<<blocks, threads, 0, stream>>>(
        hist, W1, b1, W2, b2, W3, b3, out);
}